// Round 8
// baseline (5342.805 us; speedup 1.0000x reference)
//
#include <hip/hip_runtime.h>

// ---------------------------------------------------------------------------
// LayerNorm-LSTM (2 layers) + softmax head.  B=1024 T=100 D=300 U=512 C=14
// Round 11:
//   - r7: 5156us, best.  gemm_x0 (455us, write-bound on its own 400MB
//     output) eliminated: x@W0 fused into gemm_step prob0 (K 512->832,
//     still < prob1's K=1024 critical path -> free).  x repacked once to
//     f16 xh[t][b][320] (65MB, ~60us).
//   - gemm_step was 1 block/CU = 1 wave/SIMD (zero TLP).  Now 128x64 tile,
//     grid (32,16) = 512 blocks = 2 waves/SIMD, ~150 VGPR under (256,2),
//     4-deep pipeline kept (PIPE4 for K%128==0, PIPE2 for K=320).
//   - pipeline skew unchanged: z0(t) || z1(t-1), 2 launches/step, fp32 z.
// ---------------------------------------------------------------------------

typedef _Float16 f16;
typedef _Float16 f16x8 __attribute__((ext_vector_type(8)));
typedef _Float16 f16x4 __attribute__((ext_vector_type(4)));
typedef float f32x4 __attribute__((ext_vector_type(4)));

// ---------------------------------------------------------------------------
// W [K,N] fp32 row-major -> Bt [N,Kp] f16 row-major at column offset k_off.
// ---------------------------------------------------------------------------
__global__ __launch_bounds__(256) void transpose_f16(
    const float* __restrict__ W, f16* __restrict__ Bt, int K, int N, int Kp,
    int k_off) {
  __shared__ float s[32][33];
  int n0 = blockIdx.x * 32, k0 = blockIdx.y * 32;
  int tid = threadIdx.x, c = tid & 31, r8 = tid >> 5;
  for (int rr = r8; rr < 32; rr += 8) {
    int k = k0 + rr;
    s[rr][c] = (k < K) ? W[(long)k * N + (n0 + c)] : 0.0f;
  }
  __syncthreads();
  for (int rr = r8; rr < 32; rr += 8)
    Bt[(long)(n0 + rr) * Kp + k_off + (k0 + c)] = (f16)s[c][rr];
}

// ---------------------------------------------------------------------------
// x fp32 -> xh f16 padded to 320 cols.
//   tmode=1: row r = t*1024+b (t=r>>10, b=r&1023), src = x[b][t][:], rows=102400
//   tmode=0: src row r at x + r*lda (per-step fallback), rows=1024
// Each thread converts 8 elements.
// ---------------------------------------------------------------------------
__global__ __launch_bounds__(256) void convert_x(
    const float* __restrict__ x, long lda, f16* __restrict__ xh, int rows,
    int tmode) {
  int idx = blockIdx.x * 256 + threadIdx.x;
  if (idx >= rows * 40) return;
  int r = idx / 40, c8 = (idx - r * 40) * 8;
  const float* src;
  if (tmode) {
    int t = r >> 10, b = r & 1023;
    src = x + (long)b * 30000 + (long)t * 300;
  } else {
    src = x + (long)r * lda;
  }
  f16x8 h8;
  if (c8 + 8 <= 300) {
    f32x4 lo = *(const f32x4*)(src + c8);
    f32x4 hi = *(const f32x4*)(src + c8 + 4);
#pragma unroll
    for (int e = 0; e < 4; ++e) {
      h8[e] = (f16)lo[e];
      h8[4 + e] = (f16)hi[e];
    }
  } else {
#pragma unroll
    for (int e = 0; e < 8; ++e) {
      int k = c8 + e;
      h8[e] = (k < 300) ? (f16)src[k] : (f16)0.f;
    }
  }
  *(f16x8*)(xh + (long)r * 320 + c8) = h8;
}

// --------------------------- gemm_step tiles -------------------------------
// wave tile 64x32: 4 A-frags x 2 B-frags, acc[4][2] f32x4 (32 VGPR).
#define LD6(AF, BF, A0, LDA, B0, LDB, K0)                  \
  AF[0] = *(const f16x8*)((A0) + (K0));                    \
  AF[1] = *(const f16x8*)((A0) + 16 * (LDA) + (K0));       \
  AF[2] = *(const f16x8*)((A0) + 32 * (LDA) + (K0));       \
  AF[3] = *(const f16x8*)((A0) + 48 * (LDA) + (K0));       \
  BF[0] = *(const f16x8*)((B0) + (K0));                    \
  BF[1] = *(const f16x8*)((B0) + 16 * (LDB) + (K0));

#define MM8(AF, BF)                                                               \
  {                                                                               \
    _Pragma("unroll") for (int i_ = 0; i_ < 4; ++i_)                              \
    _Pragma("unroll") for (int j_ = 0; j_ < 2; ++j_)                              \
      acc[i_][j_] = __builtin_amdgcn_mfma_f32_16x16x32_f16(AF[i_], BF[j_],        \
                                                            acc[i_][j_], 0, 0, 0); \
  }

// 4-deep register pipeline; KTOT must be a multiple of 128.
#define PIPE4(A0, LDA, B0, LDB, KTOT)                            \
  {                                                              \
    f16x8 aA[4], bA[2], aB[4], bB[2];                            \
    f16x8 aC[4], bC[2], aD[4], bD[2];                            \
    LD6(aA, bA, A0, LDA, B0, LDB, 0)                             \
    LD6(aB, bB, A0, LDA, B0, LDB, 32)                            \
    LD6(aC, bC, A0, LDA, B0, LDB, 64)                            \
    LD6(aD, bD, A0, LDA, B0, LDB, 96)                            \
    for (int k0 = 0; k0 + 224 < (KTOT); k0 += 128) {             \
      MM8(aA, bA) LD6(aA, bA, A0, LDA, B0, LDB, k0 + 128)        \
      MM8(aB, bB) LD6(aB, bB, A0, LDA, B0, LDB, k0 + 160)        \
      MM8(aC, bC) LD6(aC, bC, A0, LDA, B0, LDB, k0 + 192)        \
      MM8(aD, bD) LD6(aD, bD, A0, LDA, B0, LDB, k0 + 224)        \
    }                                                            \
    MM8(aA, bA) MM8(aB, bB) MM8(aC, bC) MM8(aD, bD)              \
  }

// 2-deep register pipeline; KTOT any multiple of 64 ... +32 (used for 320).
#define PIPE2(A0, LDA, B0, LDB, KTOT)                            \
  {                                                              \
    f16x8 aE[4], bE[2], aF[4], bF[2];                            \
    LD6(aE, bE, A0, LDA, B0, LDB, 0)                             \
    int k0 = 0;                                                  \
    for (; k0 + 64 < (KTOT); k0 += 64) {                         \
      LD6(aF, bF, A0, LDA, B0, LDB, k0 + 32)                     \
      MM8(aE, bE)                                                \
      LD6(aE, bE, A0, LDA, B0, LDB, k0 + 64)                     \
      MM8(aF, bF)                                                \
    }                                                            \
    LD6(aF, bF, A0, LDA, B0, LDB, k0 + 32)                       \
    MM8(aE, bE) MM8(aF, bF)                                      \
  }

// ---------------------------------------------------------------------------
// Combined per-step GEMM (pipelined layers), fp32 output:
//   y in [0,8):   zA[mstripe y]   = xh_t @ W0t + h0 @ U0t   (z0 at step t)
//   y in [8,16):  zB[mstripe y-8] = h01 @ WU1t  (K=1024)    (z1 at step t-1)
// xh_t [1024][320] f16; h01 [1024][1024] f16 (h0 cols [0,512));
// W0t [2048][320]; U0t [2048][512]; WU1t [2048][1024].
// Block tile 128x64 (waves 2x2 of 64x32), grid (32,16) = 512 blocks
// = 2 blocks/CU = 2 waves/SIMD.  ~150 VGPR under launch_bounds(256,2).
// ---------------------------------------------------------------------------
__global__ __launch_bounds__(256, 2) void gemm_step(
    const f16* __restrict__ xh_t, const f16* __restrict__ h01,
    const f16* __restrict__ W0t, const f16* __restrict__ U0t,
    const f16* __restrict__ WU1t,
    float* __restrict__ zA, float* __restrict__ zB, int do0, int do1) {
  int y = blockIdx.y;
  int prob = y >> 3;
  if (prob ? !do1 : !do0) return;
  int tid = threadIdx.x;
  int lane = tid & 63, w = tid >> 6;
  int wr = w >> 1, wc = w & 1;
  int l15 = lane & 15, quad = lane >> 4;
  long bm0 = (long)(y & 7) * 128 + wr * 64;
  long bn0 = (long)blockIdx.x * 64 + wc * 32;

  f32x4 acc[4][2] = {};

  if (prob == 0) {
    {  // x_t @ W0, K=320 (cols 300..319 zero-padded on both operands)
      const f16* a0 = xh_t + (bm0 + l15) * 320 + quad * 8;
      const f16* b0 = W0t + (bn0 + l15) * 320L + quad * 8;
      PIPE2(a0, 320, b0, 320, 320)
    }
    {  // h0 @ U0, K=512
      const f16* a0 = h01 + (bm0 + l15) * 1024 + quad * 8;
      const f16* b0 = U0t + (bn0 + l15) * 512L + quad * 8;
      PIPE4(a0, 1024, b0, 512, 512)
    }
  } else {
    // z1(t-1) = h01 @ WU1t, K=1024
    const f16* a0 = h01 + (bm0 + l15) * 1024 + quad * 8;
    const f16* b0 = WU1t + (bn0 + l15) * 1024L + quad * 8;
    PIPE4(a0, 1024, b0, 1024, 1024)
  }

  float* Z = prob ? zB : zA;
#pragma unroll
  for (int i = 0; i < 4; ++i) {
    long row = bm0 + i * 16 + quad * 4;
#pragma unroll
    for (int j = 0; j < 2; ++j) {
      long col = bn0 + j * 16 + l15;
#pragma unroll
      for (int r = 0; r < 4; ++r)
        Z[(row + r) * 2048 + col] = acc[i][j][r];
    }
  }
}

// ---------------------------------------------------------------------------
// Combined LN + gates + state update (fp32 z, vectorized):
//   blocks [0,1024)    : layer 0, z=zA, mask time t     (if do0)
//   blocks [1024,2048) : layer 1, z=zB, mask time t-1   (if do1)
// h stored into h01 (row stride 1024, layer offset 512*layer).
// ---------------------------------------------------------------------------
__global__ __launch_bounds__(256) void ln_gates2(
    const float* __restrict__ zA, const float* __restrict__ zB,
    const float* __restrict__ g0, const float* __restrict__ be0,
    const float* __restrict__ bs0, const float* __restrict__ g1,
    const float* __restrict__ be1, const float* __restrict__ bs1,
    const int* __restrict__ mask, int t,
    f16* __restrict__ h01, float* __restrict__ c0, float* __restrict__ c1,
    int do0, int do1) {
  __shared__ float act[2048];
  int layer = blockIdx.x >> 10;
  if (layer ? !do1 : !do0) return;
  int b = blockIdx.x & 1023;
  const float* z = layer ? zB : zA;
  const float* gamma = layer ? g1 : g0;
  const float* beta = layer ? be1 : be0;
  const float* bias = layer ? bs1 : bs0;
  f16* h = h01 + layer * 512;
  float* c = layer ? c1 : c0;
  int tm = layer ? (t - 1) : t;

  int tid = threadIdx.x;
  int w = tid >> 6, lane = tid & 63;

  const float* zb = z + (long)b * 2048 + w * 512;
  f32x4 zv[2];
  float sum = 0.0f, sq = 0.0f;
#pragma unroll
  for (int i = 0; i < 2; ++i) {
    f32x4 v = *(const f32x4*)(zb + lane * 4 + 256 * i);
    zv[i] = v;
#pragma unroll
    for (int e = 0; e < 4; ++e) {
      sum += v[e];
      sq += v[e] * v[e];
    }
  }
#pragma unroll
  for (int off = 32; off; off >>= 1) {
    sum += __shfl_xor(sum, off);
    sq += __shfl_xor(sq, off);
  }
  float mu = sum * (1.0f / 512.0f);
  float var = sq * (1.0f / 512.0f) - mu * mu;
  float is = rsqrtf(var + 1e-3f);

#pragma unroll
  for (int i = 0; i < 2; ++i) {
    int k = w * 512 + lane * 4 + 256 * i;
    f32x4 g = *(const f32x4*)(gamma + k);
    f32x4 be = *(const f32x4*)(beta + k);
    f32x4 bi = *(const f32x4*)(bias + k);
    f32x4 av;
#pragma unroll
    for (int e = 0; e < 4; ++e) {
      float val = g[e] * (zv[i][e] - mu) * is + be[e] + bi[e];
      float a;
      if (w == 2) {
        a = 2.0f / (1.0f + __expf(-2.0f * val)) - 1.0f;  // tanh
      } else {
        a = 1.0f / (1.0f + __expf(-val));                // sigmoid
      }
      av[e] = a;
    }
    *(f32x4*)(act + k) = av;
  }
  __syncthreads();

  bool m = mask[(long)b * 100 + tm] > 0;
#pragma unroll
  for (int i = 0; i < 2; ++i) {
    int u = tid + 256 * i;
    float co = c[(long)b * 512 + u];
    float ho = (float)h[(long)b * 1024 + u];
    float cn = act[512 + u] * co + act[u] * act[1024 + u];
    float th = 2.0f / (1.0f + __expf(-2.0f * cn)) - 1.0f;
    float hn = act[1536 + u] * th;
    h[(long)b * 1024 + u] = (f16)(m ? hn : ho);
    c[(long)b * 512 + u] = m ? cn : co;
  }
}

// ---------------------------------------------------------------------------
// Head: out[b,:] = softmax(h1[b,:] @ Wd + bd); h1 = h01 cols [512,1024)
// ---------------------------------------------------------------------------
__global__ __launch_bounds__(64) void head_kernel(
    const f16* __restrict__ h01, const float* __restrict__ Wd,
    const float* __restrict__ bd, float* __restrict__ out) {
  __shared__ float hs[512];
  __shared__ float lg[16];
  int b = blockIdx.x, tid = threadIdx.x;
#pragma unroll
  for (int i = 0; i < 8; ++i)
    hs[tid + 64 * i] = (float)h01[(long)b * 1024 + 512 + tid + 64 * i];
  __syncthreads();
  if (tid < 14) {
    float s = bd[tid];
    for (int k = 0; k < 512; ++k) s += hs[k] * Wd[k * 14 + tid];
    lg[tid] = s;
  }
  __syncthreads();
  if (tid < 14) {
    float mx = lg[0];
#pragma unroll
    for (int i = 1; i < 14; ++i) mx = fmaxf(mx, lg[i]);
    float e = __expf(lg[tid] - mx);
    float den = 0.0f;
#pragma unroll
    for (int i = 0; i < 14; ++i) den += __expf(lg[i] - mx);
    out[(long)b * 14 + tid] = e / den;
  }
}

// ---------------------------------------------------------------------------
extern "C" void kernel_launch(void* const* d_in, const int* in_sizes, int n_in,
                              void* d_out, int out_size, void* d_ws, size_t ws_size,
                              hipStream_t stream) {
  const float* x   = (const float*)d_in[0];
  const int* mask  = (const int*)d_in[1];
  const float* W0  = (const float*)d_in[2];
  const float* U0w = (const float*)d_in[3];
  const float* b0  = (const float*)d_in[4];
  const float* g0  = (const float*)d_in[5];
  const float* be0 = (const float*)d_in[6];
  const float* W1  = (const float*)d_in[7];
  const float* U1w = (const float*)d_in[8];
  const float* b1  = (const float*)d_in[9];
  const float* g1  = (const float*)d_in[10];
  const float* be1 = (const float*)d_in[11];
  const float* Wd  = (const float*)d_in[12];
  const float* bd  = (const float*)d_in[13];
  float* out = (float*)d_out;

  char* p = (char*)d_ws;
  const size_t MB = (size_t)1 << 20;
  f16*   h01  = (f16*)(p + 0);               // 2 MiB  [1024][1024]
  float* c0   = (float*)(p + 2 * MB);        // 2 MiB
  float* c1   = (float*)(p + 4 * MB);        // 2 MiB
  float* zA   = (float*)(p + 6 * MB);        // 8 MiB  [1024][2048] fp32
  float* zB   = (float*)(p + 14 * MB);       // 8 MiB
  f16*   W0t  = (f16*)(p + 22 * MB);         // 1.25 MiB
  f16*   U0t  = (f16*)(p + 22 * MB + 1310720);            // 2 MiB
  f16*   WU1t = (f16*)(p + 22 * MB + 1310720 + 2097152);  // 4 MiB -> ends ~29.25
  f16*   xh   = (f16*)(p + 30 * MB);         // [100][1024][320] f16 = 62.5 MiB
                                             // -> ends 92.5 MiB
  const bool fullx = ws_size >= (size_t)93 * MB;

  // zero h01, c0, c1 (ws is re-poisoned before every call)
  hipMemsetAsync(p, 0, 6 * MB, stream);

  // weight prep
  transpose_f16<<<dim3(64, 10), 256, 0, stream>>>(W0,  W0t, 300, 2048, 320, 0);
  transpose_f16<<<dim3(64, 16), 256, 0, stream>>>(U0w, U0t, 512, 2048, 512, 0);
  transpose_f16<<<dim3(64, 16), 256, 0, stream>>>(W1,  WU1t, 512, 2048, 1024, 0);
  transpose_f16<<<dim3(64, 16), 256, 0, stream>>>(U1w, WU1t, 512, 2048, 1024, 512);

  if (fullx) {
    // x -> f16 [t][b][320] once (contiguous A-slice per step)
    convert_x<<<(102400 * 40 + 255) / 256, 256, 0, stream>>>(x, 0, xh, 102400, 1);
  }

  // pipelined: iteration t computes z0(t) and z1(t-1) together.
  for (int t = 0; t <= 100; ++t) {
    int do0 = (t < 100) ? 1 : 0;
    int do1 = (t >= 1) ? 1 : 0;
    const f16* xh_t;
    if (fullx) {
      xh_t = xh + (long)t * 1024 * 320;
    } else {
      // per-step conversion into a small slice buffer at xh base
      if (do0)
        convert_x<<<(1024 * 40 + 255) / 256, 256, 0, stream>>>(
            x + (long)t * 300, 30000, (f16*)(p + 30 * MB), 1024, 0);
      xh_t = (const f16*)(p + 30 * MB);
    }
    gemm_step<<<dim3(32, 16), 256, 0, stream>>>(
        xh_t, h01, W0t, U0t, WU1t, zA, zB, do0, do1);
    ln_gates2<<<2048, 256, 0, stream>>>(
        zA, zB, g0, be0, b0, g1, be1, b1, mask, t, h01, c0, c1, do0, do1);
  }

  head_kernel<<<1024, 64, 0, stream>>>(h01, Wd, bd, out);
}